// Round 1
// baseline (291.734 us; speedup 1.0000x reference)
//
#include <hip/hip_runtime.h>
#include <math.h>

#define B_ 64
#define IC 2048
#define OC 32
#define OD 16
#define ID 8

// ---------------------------------------------------------------------------
// Phase A: partial s accumulation over i-chunks.
//   s[b,o,d] = sum_i c[b,i,o] * (sum_m W[i,o,d,m] * x[b,i,m])
// grid: 2*NCH blocks (blockIdx = oh + 2*ch), 256 threads.
// Each thread owns one (o,d) slot and accumulates for all 64 b.
// ---------------------------------------------------------------------------
template<bool UNIFORM, int NCH>
__global__ __launch_bounds__(256) void phaseA(
    const float* __restrict__ x, const float* __restrict__ W,
    const float* __restrict__ bl, const float* __restrict__ mz,
    float* __restrict__ part)
{
  constexpr int CI = IC / NCH;
  const int t  = threadIdx.x;
  const int oh = blockIdx.x & 1;
  const int ch = blockIdx.x >> 1;
  const int o  = oh * 16 + (t >> 4);
  const int d  = t & 15;
  const int i0 = ch * CI;

  __shared__ float c_lds[B_ * OC];     // c[b][o] for current i
  __shared__ float x_lds[B_][ID];      // x[b][m] for current i

  float acc[B_];
#pragma unroll
  for (int b = 0; b < B_; ++b) acc[b] = 0.f;

  // W float4 index: i*1024 + o*32 + d*2
  const float4* wbase = (const float4*)W;
  const int wIdx = o * 32 + d * 2;
  float4 w0 = wbase[(size_t)i0 * 1024 + wIdx];
  float4 w1 = wbase[(size_t)i0 * 1024 + wIdx + 1];

  for (int ii = 0; ii < CI; ++ii) {
    const int i = i0 + ii;
    __syncthreads();   // protect LDS reads of previous iteration
    {
      const int idx = t * 2;
      const int b0 = idx >> 3, m0 = idx & 7;
      *(float2*)&x_lds[b0][m0] =
          *(const float2*)(x + (size_t)b0 * (IC * ID) + (size_t)i * ID + m0);
    }
    if constexpr (!UNIFORM) {
#pragma unroll
      for (int p = 0; p < 8; ++p) {
        const int j = t + 256 * p;                       // j = b*32 + o
        c_lds[j] = __expf(bl[(size_t)i * 2048 + j] - mz[j]) * mz[2048 + j];
      }
    }
    __syncthreads();

    // prefetch next W
    const int inext = (ii + 1 < CI) ? (i + 1) : i;
    const float4 nw0 = wbase[(size_t)inext * 1024 + wIdx];
    const float4 nw1 = wbase[(size_t)inext * 1024 + wIdx + 1];

#pragma unroll
    for (int b = 0; b < B_; ++b) {
      const float4 xa = *(const float4*)&x_lds[b][0];
      const float4 xb = *(const float4*)&x_lds[b][4];
      float tmp = w0.x * xa.x + w0.y * xa.y + w0.z * xa.z + w0.w * xa.w
                + w1.x * xb.x + w1.y * xb.y + w1.z * xb.z + w1.w * xb.w;
      if constexpr (UNIFORM) acc[b] += tmp;
      else                   acc[b] = fmaf(c_lds[b * OC + o], tmp, acc[b]);
    }
    w0 = nw0; w1 = nw1;
  }

  // write partials: part[ch][b][o][d]
  float* pp = part + (size_t)ch * (B_ * OC * OD) + o * OD + d;
#pragma unroll
  for (int b = 0; b < B_; ++b) pp[(size_t)b * (OC * OD)] = acc[b];
}

// ---------------------------------------------------------------------------
// Reduce partials over chunks, then squash. Writes v (or d_out on last iter).
// grid: 128 blocks x 256 threads; one thread per (b,o,d).
// ---------------------------------------------------------------------------
template<int NCH>
__global__ __launch_bounds__(256) void reduceSquash(
    const float* __restrict__ part, float* __restrict__ vout, float scale)
{
  const int g = blockIdx.x * 256 + threadIdx.x;   // g = b*512 + o*16 + d
  float s = 0.f;
#pragma unroll 8
  for (int ch = 0; ch < NCH; ++ch) s += part[(size_t)ch * 32768 + g];
  s *= scale;

  float sq = s * s;
#pragma unroll
  for (int k = 1; k < 16; k <<= 1) sq += __shfl_xor(sq, k);   // sum over d (16 lanes)

  const float f = (sq / (1.f + sq)) * rsqrtf(sq + 1e-9f);
  vout[g] = s * f;
}

// ---------------------------------------------------------------------------
// Phase B: b_logits[i][b][o] (+)= sum_d (sum_m W[i,o,d,m]*x[b,i,m]) * v[b,o,d]
// grid: 2048 blocks (one per i), 256 threads. W[i] staged in LDS once.
// ---------------------------------------------------------------------------
template<bool FIRST>
__global__ __launch_bounds__(256) void phaseB(
    const float* __restrict__ x, const float* __restrict__ W,
    const float* __restrict__ v, float* __restrict__ bl)
{
  const int t = threadIdx.x;
  const int i = blockIdx.x;
  const int b = t & 63;
  const int w = t >> 6;      // wave id: handles o in [w*8, w*8+8)

  __shared__ float W_lds[OC * OD * ID];   // 4096 floats = 16 KB
  __shared__ float x_lds[B_][ID];

  {
    const float4* Wg = (const float4*)(W + (size_t)i * 4096);
#pragma unroll
    for (int k = 0; k < 4; ++k)
      *(float4*)&W_lds[t * 4 + k * 1024] = Wg[t + k * 256];
  }
  {
    const int idx = t * 2;
    const int b0 = idx >> 3, m0 = idx & 7;
    *(float2*)&x_lds[b0][m0] =
        *(const float2*)(x + (size_t)b0 * (IC * ID) + (size_t)i * ID + m0);
  }
  __syncthreads();

  float xr[8];
#pragma unroll
  for (int m = 0; m < 8; ++m) xr[m] = x_lds[b][m];

  float delta[8];
#pragma unroll
  for (int p = 0; p < 8; ++p) {
    const int o = w * 8 + p;
    const float* vv = v + ((size_t)b * OC + o) * OD;
    const float4 v0 = *(const float4*)(vv);
    const float4 v1 = *(const float4*)(vv + 4);
    const float4 v2 = *(const float4*)(vv + 8);
    const float4 v3 = *(const float4*)(vv + 12);
    const float vr[16] = {v0.x, v0.y, v0.z, v0.w, v1.x, v1.y, v1.z, v1.w,
                          v2.x, v2.y, v2.z, v2.w, v3.x, v3.y, v3.z, v3.w};
    float out = 0.f;
#pragma unroll
    for (int dd = 0; dd < 16; ++dd) {
      const float4 wa = *(const float4*)&W_lds[o * 128 + dd * 8];
      const float4 wb = *(const float4*)&W_lds[o * 128 + dd * 8 + 4];
      const float tmp = wa.x * xr[0] + wa.y * xr[1] + wa.z * xr[2] + wa.w * xr[3]
                      + wb.x * xr[4] + wb.y * xr[5] + wb.z * xr[6] + wb.w * xr[7];
      out = fmaf(vr[dd], tmp, out);
    }
    delta[p] = out;
  }

  float* blp = bl + (size_t)i * 2048 + b * 32 + w * 8;
  if constexpr (FIRST) {
    *(float4*)blp       = make_float4(delta[0], delta[1], delta[2], delta[3]);
    *(float4*)(blp + 4) = make_float4(delta[4], delta[5], delta[6], delta[7]);
  } else {
    float4 o0 = *(const float4*)blp;
    float4 o1 = *(const float4*)(blp + 4);
    o0.x += delta[0]; o0.y += delta[1]; o0.z += delta[2]; o0.w += delta[3];
    o1.x += delta[4]; o1.y += delta[5]; o1.z += delta[6]; o1.w += delta[7];
    *(float4*)blp       = o0;
    *(float4*)(blp + 4) = o1;
  }
}

// ---------------------------------------------------------------------------
// Softmax stats over i (per (b,o) pair), two-level online reduction.
// statsK: grid 128 (i-chunks of 16); mergeK: grid 8.
// ---------------------------------------------------------------------------
__global__ __launch_bounds__(256) void statsK(
    const float* __restrict__ bl, float* __restrict__ spm, float* __restrict__ spz)
{
  const int t = threadIdx.x, ch = blockIdx.x;
  float m[8], Z[8];
#pragma unroll
  for (int p = 0; p < 8; ++p) { m[p] = -3.0e38f; Z[p] = 0.f; }
  for (int ii = 0; ii < 16; ++ii) {
    const int i = ch * 16 + ii;
#pragma unroll
    for (int p = 0; p < 8; ++p) {
      const float val = bl[(size_t)i * 2048 + t + 256 * p];
      const float nm = fmaxf(m[p], val);
      Z[p] = Z[p] * __expf(m[p] - nm) + __expf(val - nm);
      m[p] = nm;
    }
  }
#pragma unroll
  for (int p = 0; p < 8; ++p) {
    spm[(size_t)ch * 2048 + t + 256 * p] = m[p];
    spz[(size_t)ch * 2048 + t + 256 * p] = Z[p];
  }
}

__global__ __launch_bounds__(256) void mergeK(
    const float* __restrict__ spm, const float* __restrict__ spz,
    float* __restrict__ mz)
{
  const int j = blockIdx.x * 256 + threadIdx.x;   // 2048 (b,o) pairs
  float m = -3.0e38f, Z = 0.f;
  for (int ch = 0; ch < 128; ++ch) {
    const float cm = spm[(size_t)ch * 2048 + j];
    const float cz = spz[(size_t)ch * 2048 + j];
    const float nm = fmaxf(m, cm);
    Z = Z * __expf(m - nm) + cz * __expf(cm - nm);
    m = nm;
  }
  mz[j] = m;
  mz[2048 + j] = 1.f / Z;
}

// ---------------------------------------------------------------------------
extern "C" void kernel_launch(void* const* d_in, const int* in_sizes, int n_in,
                              void* d_out, int out_size, void* d_ws, size_t ws_size,
                              hipStream_t stream) {
  const float* x = (const float*)d_in[0];
  const float* W = (const float*)d_in[1];   // [1] leading dim: data starts here
  float* out = (float*)d_out;
  float* ws = (float*)d_ws;

  // workspace layout (floats), parameterized by NCH (phase-A chunk count)
  auto run = [&](auto nch_tag) {
    constexpr int NCH = decltype(nch_tag)::value;
    float* bl   = ws;                                // [2048][64][32]
    float* part = bl + (size_t)IC * B_ * OC;         // [NCH][64][32][16]
    float* spm  = part + (size_t)NCH * 32768;        // [128][2048]
    float* spz  = spm + 128 * 2048;                  // [128][2048]
    float* mz   = spz + 128 * 2048;                  // m[2048], rZ[2048]
    float* v    = mz + 4096;                         // [64][32][16]

    // -------- iteration 1 (c uniform = 1/2048) --------
    phaseA<true, NCH><<<dim3(2 * NCH), dim3(256), 0, stream>>>(x, W, nullptr, nullptr, part);
    reduceSquash<NCH><<<dim3(128), dim3(256), 0, stream>>>(part, v, 1.f / 2048.f);
    phaseB<true><<<dim3(2048), dim3(256), 0, stream>>>(x, W, v, bl);

    // -------- iteration 2 --------
    statsK<<<dim3(128), dim3(256), 0, stream>>>(bl, spm, spz);
    mergeK<<<dim3(8), dim3(256), 0, stream>>>(spm, spz, mz);
    phaseA<false, NCH><<<dim3(2 * NCH), dim3(256), 0, stream>>>(x, W, bl, mz, part);
    reduceSquash<NCH><<<dim3(128), dim3(256), 0, stream>>>(part, v, 1.f);
    phaseB<false><<<dim3(2048), dim3(256), 0, stream>>>(x, W, v, bl);

    // -------- iteration 3 (no b-update needed) --------
    statsK<<<dim3(128), dim3(256), 0, stream>>>(bl, spm, spz);
    mergeK<<<dim3(8), dim3(256), 0, stream>>>(spm, spz, mz);
    phaseA<false, NCH><<<dim3(2 * NCH), dim3(256), 0, stream>>>(x, W, bl, mz, part);
    reduceSquash<NCH><<<dim3(128), dim3(256), 0, stream>>>(part, out, 1.f);
  };

  const size_t need256 =
      ((size_t)IC * B_ * OC + 256ul * 32768 + 2ul * 128 * 2048 + 4096 + 32768) * 4;
  if (ws_size >= need256) {
    run(std::integral_constant<int, 256>{});
  } else {
    run(std::integral_constant<int, 64>{});
  }
}

// Round 2
// 186.875 us; speedup vs baseline: 1.5611x; 1.5611x over previous
//
#include <hip/hip_runtime.h>
#include <math.h>

#define B_ 64
#define IC 2048
#define OC 32
#define OD 16
#define ID 8

__device__ __forceinline__ float dot8(const float4 w0, const float4 w1,
                                      const float4 xa, const float4 xb) {
  return w0.x*xa.x + w0.y*xa.y + w0.z*xa.z + w0.w*xa.w
       + w1.x*xb.x + w1.y*xb.y + w1.z*xb.z + w1.w*xb.w;
}

// ---------------------------------------------------------------------------
// Fused routing kernel: recomputes u_hat[b,i,o,d] once and uses it for BOTH
// the b-logit update (previous iteration's phaseB) and the weighted s
// accumulation (current iteration's phaseA) with UNNORMALIZED p=exp(b);
// the softmax denominator Z is accumulated separately and applied in
// reduceSquash (linearity of the s-einsum).
//
// MODE 0: iter1, uniform c (no v, no exp). MODE 1: iter2, b_old=0, writes bl.
// MODE 2: iter3, reads bl.
//
// grid: 2*NCH blocks (ch = bid>>1 over i-chunks, bh = bid&1 over b-halves).
// 256 threads: slot=t&127 -> o=slot>>2 (32), dq=slot&3 (d-quad); bg=t>>7.
// Thread owns (o, d in [dq*4,dq*4+4)) for 16 b's. acc = float4[16].
// dq lanes are adjacent -> d-reduction for Delta is 2x shfl_xor.
// ---------------------------------------------------------------------------
template<int MODE, int NCH>
__global__ __launch_bounds__(256) void fusedK(
    const float* __restrict__ x, const float* __restrict__ W,
    const float* __restrict__ v, const float* __restrict__ blin,
    float* __restrict__ blout, float* __restrict__ part,
    float* __restrict__ zpart)
{
  constexpr int CI = IC / NCH;
  const int t    = threadIdx.x;
  const int ch   = blockIdx.x >> 1;
  const int bh   = blockIdx.x & 1;
  const int slot = t & 127;
  const int bg   = t >> 7;
  const int o    = slot >> 2;
  const int dq   = slot & 3;
  const int i0   = ch * CI;
  const int bbase = bh * 32 + bg * 16;

  __shared__ float4 xs[32][16];                      // x[b-local][ii2*2+half], 8 i's
  __shared__ float  bls[(MODE == 2) ? 8 * 1024 : 4]; // bl[ii2][b-local*32+o]

  float4 accv[16];
  float  zacc[16];
  float4 vreg[16];
#pragma unroll
  for (int bb = 0; bb < 16; ++bb) { accv[bb] = make_float4(0,0,0,0); zacc[bb] = 0.f; }

  if constexpr (MODE != 0) {
#pragma unroll
    for (int bb = 0; bb < 16; ++bb)
      vreg[bb] = *(const float4*)(v + ((bbase + bb) * 32 + o) * 16 + dq * 4);
  }

  const float4* Wg = (const float4*)W;
  const float4* xg = (const float4*)x;
  const int wIdx = o * 32 + dq * 8;

  float4 wc[8], wn[8];
#pragma unroll
  for (int r = 0; r < 8; ++r) wc[r] = Wg[(size_t)i0 * 1024 + wIdx + r];

  for (int is = 0; is < CI; is += 8) {
    __syncthreads();
    {
#pragma unroll
      for (int k = 0; k < 2; ++k) {
        const int fidx = t + 256 * k;
        const int bb = fidx >> 4, j = fidx & 15;
        xs[bb][j] = xg[(size_t)(bh * 32 + bb) * 4096 + (i0 + is) * 2 + j];
      }
      if constexpr (MODE == 2) {
        const float4* blg = (const float4*)blin;
#pragma unroll
        for (int k = 0; k < 8; ++k) {
          const int fidx = t + 256 * k;
          const int ii = fidx >> 8, r = fidx & 255;
          *(float4*)&bls[ii * 1024 + r * 4] =
              blg[(size_t)(i0 + is + ii) * 512 + bh * 256 + r];
        }
      }
    }
    __syncthreads();

    for (int ii2 = 0; ii2 < 8; ++ii2) {
      const int i = i0 + is + ii2;
      const int inext = (i + 1 < i0 + CI) ? i + 1 : i;
#pragma unroll
      for (int r = 0; r < 8; ++r) wn[r] = Wg[(size_t)inext * 1024 + wIdx + r];

#pragma unroll
      for (int bb = 0; bb < 16; ++bb) {
        const int xb = bg * 16 + bb;
        const float4 xa = xs[xb][ii2 * 2];       // wave-uniform -> LDS broadcast
        const float4 xc = xs[xb][ii2 * 2 + 1];
        float4 u;
        u.x = dot8(wc[0], wc[1], xa, xc);
        u.y = dot8(wc[2], wc[3], xa, xc);
        u.z = dot8(wc[4], wc[5], xa, xc);
        u.w = dot8(wc[6], wc[7], xa, xc);
        if constexpr (MODE == 0) {
          accv[bb].x += u.x; accv[bb].y += u.y;
          accv[bb].z += u.z; accv[bb].w += u.w;
        } else {
          const float4 vv = vreg[bb];
          float pd = u.x * vv.x + u.y * vv.y + u.z * vv.z + u.w * vv.w;
          pd += __shfl_xor(pd, 1);               // reduce over dq (lane bits 0-1)
          pd += __shfl_xor(pd, 2);
          float bnew = pd;
          if constexpr (MODE == 2) bnew += bls[ii2 * 1024 + xb * 32 + o];
          if constexpr (MODE == 1) {
            if (dq == 0)
              blout[(size_t)i * 2048 + (bh * 32 + xb) * 32 + o] = bnew;
          }
          const float p = __expf(bnew);
          accv[bb].x = fmaf(p, u.x, accv[bb].x);
          accv[bb].y = fmaf(p, u.y, accv[bb].y);
          accv[bb].z = fmaf(p, u.z, accv[bb].z);
          accv[bb].w = fmaf(p, u.w, accv[bb].w);
          zacc[bb] += p;
        }
      }
#pragma unroll
      for (int r = 0; r < 8; ++r) wc[r] = wn[r];
    }
  }

  // epilogue: part[ch][b][o][d] (f4 at dq), zpart[ch][b*32+o]
  float4* part4 = (float4*)part;
#pragma unroll
  for (int bb = 0; bb < 16; ++bb) {
    const int b = bbase + bb;
    part4[((size_t)ch * 64 + b) * 128 + o * 4 + dq] = accv[bb];
    if constexpr (MODE != 0) {
      if (dq == 0) zpart[(size_t)ch * 2048 + b * 32 + o] = zacc[bb];
    }
  }
}

// ---------------------------------------------------------------------------
// Reduce s partials over chunks, normalize by Z (or uniform scale), squash.
// grid 128 x 256; one thread per (b,o,d); g = b*512 + o*16 + d.
// ---------------------------------------------------------------------------
template<bool WITH_Z, int NCH>
__global__ __launch_bounds__(256) void reduceSquash(
    const float* __restrict__ part, const float* __restrict__ rz,
    float* __restrict__ vout, float scale)
{
  const int g = blockIdx.x * 256 + threadIdx.x;
  float s = 0.f;
#pragma unroll 8
  for (int ch = 0; ch < NCH; ++ch) s += part[(size_t)ch * 32768 + g];
  if constexpr (WITH_Z) s *= rz[g >> 4];
  else                  s *= scale;

  float sq = s * s;
#pragma unroll
  for (int k = 1; k < 16; k <<= 1) sq += __shfl_xor(sq, k);   // sum over d
  const float f = (sq / (1.f + sq)) * rsqrtf(sq + 1e-9f);
  vout[g] = s * f;
}

// ---------------------------------------------------------------------------
// Z reduction: rz[b*32+o] = 1 / sum_ch zpart[ch][b*32+o]. grid 8 x 256.
// ---------------------------------------------------------------------------
template<int NCH>
__global__ __launch_bounds__(256) void zredK(
    const float* __restrict__ zpart, float* __restrict__ rz)
{
  const int j = blockIdx.x * 256 + threadIdx.x;
  float zs = 0.f;
#pragma unroll 8
  for (int ch = 0; ch < NCH; ++ch) zs += zpart[(size_t)ch * 2048 + j];
  rz[j] = 1.f / zs;
}

// ---------------------------------------------------------------------------
extern "C" void kernel_launch(void* const* d_in, const int* in_sizes, int n_in,
                              void* d_out, int out_size, void* d_ws, size_t ws_size,
                              hipStream_t stream) {
  const float* x = (const float*)d_in[0];
  const float* W = (const float*)d_in[1];
  float* out = (float*)d_out;
  float* ws  = (float*)d_ws;

  auto run = [&](auto tag) {
    constexpr int NCH = decltype(tag)::value;
    float* bl    = ws;                                 // [2048][64][32]
    float* part  = bl + (size_t)IC * B_ * OC;          // [NCH][64][32][16]
    float* zpart = part + (size_t)NCH * 32768;         // [NCH][2048]
    float* rz    = zpart + (size_t)NCH * 2048;         // [2048]
    float* v     = rz + 2048;                          // [64][32][16]

    const dim3 gF(2 * NCH), b256(256);
    // iter 1: uniform c = 1/2048
    fusedK<0, NCH><<<gF, b256, 0, stream>>>(x, W, nullptr, nullptr, nullptr, part, nullptr);
    reduceSquash<false, NCH><<<dim3(128), b256, 0, stream>>>(part, nullptr, v, 1.f / 2048.f);
    // iter 2: b1 = u.v1 (written to bl), s2 = sum exp(b1) u / Z
    fusedK<1, NCH><<<gF, b256, 0, stream>>>(x, W, v, nullptr, bl, part, zpart);
    zredK<NCH><<<dim3(8), b256, 0, stream>>>(zpart, rz);
    reduceSquash<true, NCH><<<dim3(128), b256, 0, stream>>>(part, rz, v, 0.f);
    // iter 3: b2 = b1 + u.v2, s3, final v -> out
    fusedK<2, NCH><<<gF, b256, 0, stream>>>(x, W, v, bl, nullptr, part, zpart);
    zredK<NCH><<<dim3(8), b256, 0, stream>>>(zpart, rz);
    reduceSquash<true, NCH><<<dim3(128), b256, 0, stream>>>(part, rz, out, 0.f);
  };

  const size_t need256 =
      ((size_t)IC * B_ * OC + 256ul * 32768 + 256ul * 2048 + 2048 + 32768) * 4;
  if (ws_size >= need256) run(std::integral_constant<int, 256>{});
  else                    run(std::integral_constant<int, 64>{});
}